// Round 7
// baseline (372.702 us; speedup 1.0000x reference)
//
#include <hip/hip_runtime.h>
#include <hip/hip_bf16.h>
#include <math.h>

// ---------- types ----------
typedef __attribute__((ext_vector_type(8))) __bf16 bf16x8;
typedef __attribute__((ext_vector_type(4))) float f32x4;

// fp32 -> bf16 round-to-nearest-even
__device__ __forceinline__ unsigned short f2bf(float f) {
    union { float f; unsigned u; } v; v.f = f;
    unsigned r = v.u + 0x7fffu + ((v.u >> 16) & 1u);
    return (unsigned short)(r >> 16);
}
// pack two fp32 into one dword of two bf16 (lo, hi)
__device__ __forceinline__ unsigned int pk(float a, float b) {
    union { float f; unsigned u; } x, y; x.f = a; y.f = b;
    unsigned ra = (x.u + 0x7fffu + ((x.u >> 16) & 1u)) >> 16;
    unsigned rb = (y.u + 0x7fffu + ((y.u >> 16) & 1u)) & 0xffff0000u;
    return ra | rb;
}

// async global->LDS, 16 B per lane; LDS dest = wave-uniform base + lane*16
__device__ __forceinline__ void gl2lds16(const unsigned short* g, unsigned short* l) {
    __builtin_amdgcn_global_load_lds(
        (const __attribute__((address_space(1))) unsigned int*)(g),
        (__attribute__((address_space(3))) unsigned int*)(l), 16, 0, 0);
}

// ---------- setup kernel ----------
// block 0: packed membership table tbl[f] = used | (lslot+1)<<8
// blocks 1..448: weight transpose+convert, 64x64 LDS tiles
struct SetupArgs {
    const int *and_pairs, *or_pairs, *not_idx, *lidx;
    int* tbl;                       // 64 ints
    const float* W[5];
    unsigned short* WT[5];
    int K[5], N[5];
    int tstart[6];
};

__global__ __launch_bounds__(256) void setup_kernel(SetupArgs a) {
    __shared__ float tile[64][65];
    const int blk = blockIdx.x;
    const int tid = threadIdx.x;

    if (blk == 0) {
        if (tid < 64) {
            const int f = tid;
            int u = 0;
            for (int i = 0; i < 32; i++) u |= (a.and_pairs[i] == f);
            for (int i = 0; i < 16; i++) u |= (a.or_pairs[i] == f);
            int isnot = 0;
            for (int i = 0; i < 8; i++)  isnot |= (a.not_idx[i] == f);
            int ls = -1;
            for (int l = 0; l < 16; l++) if (a.lidx[l] == f) ls = l;
            if (isnot) ls = -1;          // tanh epilogue writes these slots
            a.tbl[f] = (u | isnot) | ((ls + 1) << 8);
        }
        return;
    }

    const int bx = blk - 1;
    int m = 0;
    while (bx >= a.tstart[m + 1]) m++;
    const float* src = a.W[m];
    unsigned short* dst = a.WT[m];
    const int K = a.K[m], N = a.N[m];
    const int t = bx - a.tstart[m];
    const int ntn = N >> 6;
    const int tk = t / ntn, tn = t % ntn;
    const int c = tid & 63, r0 = tid >> 6;
    #pragma unroll
    for (int r = r0; r < 64; r += 4)
        tile[r][c] = src[(size_t)(tk * 64 + r) * N + tn * 64 + c];
    __syncthreads();
    #pragma unroll
    for (int r = r0; r < 64; r += 4)
        dst[(size_t)(tn * 64 + r) * K + tk * 64 + c] = f2bf(tile[c][r]);
}

// ---------- prep kernel: pure streaming, no LDS, no syncs ----------
struct PrepArgs {
    const float* fv;
    unsigned short* fvb;
    const int* tbl;
    float* out;
};

__global__ __launch_bounds__(256) void prep_kernel(PrepArgs a) {
    const int t = blockIdx.x * 256 + threadIdx.x;   // 8 consecutive floats
    const size_t e = (size_t)t * 8;
    const int c = (int)(e & 511);
    const int f = (int)((e >> 9) & 63);
    const int b = (int)(e >> 15);
    const float4 v0 = *(const float4*)(a.fv + e);
    const float4 v1 = *(const float4*)(a.fv + e + 4);
    const int tb = a.tbl[f];                        // wave-uniform
    const int u  = tb & 0xff;
    const int ls = (tb >> 8) - 1;
    if (u) {
        uint4 o;
        o.x = pk(v0.x, v0.y); o.y = pk(v0.z, v0.w);
        o.z = pk(v1.x, v1.y); o.w = pk(v1.z, v1.w);
        ((uint4*)a.fvb)[t] = o;
    }
    if (ls >= 0) {
        float* d = a.out + ((size_t)b * 40 + 24 + ls) * 512 + c;
        *(float4*)(d)     = v0;
        *(float4*)(d + 4) = v1;
    }
}

// ---------- fused two-layer GEMM segment ----------
// Block: BM=64 rows x ALL 512 cols; L2 stage's A (=hid) is this block's L1
// output -> full MLP fused, hid lives in LDS only. 4 waves, wave w owns cols
// [w*128, +128): acc[4][8].
// A: global_load_lds, 4 buffers, staged 2 STEPS AHEAD (2x latency cover).
// B: per-lane direct global->reg 16B fragment loads (W L2-resident).
// L1 K-loop, counted waits (T4): barrier = s_waitcnt vmcnt(9) lgkmcnt(0);
// s_barrier.  CORRECTNESS REQUIRES PINNED VMEM ISSUE ORDER (round-6 NaN):
// sched_barrier(0) forces A-stage ops to issue BEFORE the B flat loads in
// the prologue and in each half-step.  Then, oldest-first order is
//   [A0, A1, B0 | A2, B1 | A3, B2 | ...]
// so at L1BAR(s): A(s) is either drained by vmcnt(9) (s=0: 10 outstanding,
// oldest=A0) or already retired by the previous MMAC's compiler-inserted
// wait on B(s-1) (issued after A(s)).  vmcnt is before s_barrier, so every
// wave's A(s) part is landed once all waves pass barrier s.  WAR on the 4
// A-buffers: reads of buf (s+2)&3 happened at half s-2 and retired before
// barrier s-1 (lgkm waits at MFMA).  sched_barrier(0) after each MMAC pins
// the MFMA cluster between its barriers (rule 18).
// hid LDS [64][512] bf16, 16B-chunk XOR swizzle -> L2-stage reads 2-way max.
// PATH 0: relu->hid(LDS)->L2->out fp32 (+bias), rows m=b*P+p, q=QBASE+p
// PATH 2: single layer, tanh->out, rows m=b*8+i, q=qmap[i]
// SRCM 0: A row m = concat(fvb[b,idx[2p]], fvb[b,idx[2p+1]]), K1=1024
// SRCM 1: A row m = fvb[b, idx[i]], K1=512
#define LOADB(DST, WTP, KD, K0)                                              \
    _Pragma("unroll") for (int ni = 0; ni < 8; ni++)                         \
        DST[ni] = *(const bf16x8*)((WTP) +                                   \
            (size_t)(wn + ni * 16 + ln15) * (KD) + (K0) + kq * 8);

#define MMAC(BF, AF)                                                         \
    _Pragma("unroll") for (int mi = 0; mi < 4; mi++)                         \
    _Pragma("unroll") for (int ni = 0; ni < 8; ni++)                         \
        acc[mi][ni] = __builtin_amdgcn_mfma_f32_16x16x32_bf16(               \
            AF[mi], BF[ni], acc[mi][ni], 0, 0, 0);

#define L1BAR()                                                              \
    asm volatile("s_waitcnt vmcnt(9) lgkmcnt(0)" ::: "memory");              \
    asm volatile("s_barrier" ::: "memory");

template <int P, int K1, int SRCM, int PATH, int QBASE>
__device__ __forceinline__ void fused_seg(
    const unsigned short* __restrict__ A,
    const int* __restrict__ idx,
    const unsigned short* __restrict__ W1T,
    const float* __restrict__ b1,
    const unsigned short* __restrict__ W2T,
    const float* __restrict__ b2,
    float* __restrict__ out,
    const int* __restrict__ leftover,
    int local,
    unsigned short* As, unsigned short* hid) {

    const int tid  = threadIdx.x;
    const int lane = tid & 63, w = tid >> 6;
    const int ln15 = lane & 15;
    const int kq   = lane >> 4;          // k-chunk quad 0..3
    const int wn   = w * 128;            // wave's col base
    const int m0   = local * 64;         // block's row base

    // --- A staging: wave w stages rows [w*16, +16); lane l -> row l>>2,
    // swizzled source k-chunk ((l&3)^((l>>2)&3))*8 shorts (16 B)
    const int skin = ((lane & 3) ^ ((lane >> 2) & 3)) * 8;
    const unsigned short *ar0, *ar1;
    {
        const int m = m0 + w * 16 + (lane >> 2);
        if constexpr (SRCM == 0) {
            const int b = m / P, p = m % P;
            ar0 = A + ((size_t)b * 64 + idx[2 * p]) * 512;
            ar1 = A + ((size_t)b * 64 + idx[2 * p + 1]) * 512;
        } else {
            const int b = m >> 3, i = m & 7;
            ar0 = A + ((size_t)b * 64 + idx[i]) * 512;
            ar1 = ar0;
        }
    }
    auto stageA = [&](int buf, int t) {
        const int k0 = t * 32;
        const unsigned short* src;
        if constexpr (SRCM == 0)
            src = (k0 >= 512 ? ar1 + (k0 - 512) : ar0 + k0) + skin;
        else
            src = ar0 + k0 + skin;
        gl2lds16(src, &As[buf * 2048 + w * 512]);
    };
    const int xsel = (kq ^ (lane & 3)) * 8;   // frag-read chunk slot

    f32x4 acc[4][8];
    #pragma unroll
    for (int mi = 0; mi < 4; mi++)
        #pragma unroll
        for (int ni = 0; ni < 8; ni++)
            acc[mi][ni] = f32x4{0.f, 0.f, 0.f, 0.f};

    bf16x8 bA[8], bB[8];

    // ---- L1: acc = A[64,K1] @ W1[K1,512] ----
    constexpr int NT1 = K1 / 32;   // even
    stageA(0, 0);                  // A0: MUST be oldest in flight
    stageA(1, 1);                  // A1
    __builtin_amdgcn_sched_barrier(0);   // pin A0,A1 before B0
    LOADB(bA, W1T, K1, 0);         // B0 x8; outstanding = [A0,A1,B0x8] = 10

    for (int h = 0; h < NT1; h += 2) {
        // even half-step: buf h&3, B = bA
        L1BAR();                                     // A(h) landed
        if (h + 2 < NT1) stageA((h + 2) & 3, h + 2); // A(h+2), 2-deep
        __builtin_amdgcn_sched_barrier(0);           // pin A before B
        LOADB(bB, W1T, K1, (h + 1) * 32);            // B(h+1)
        bf16x8 af[4];
        #pragma unroll
        for (int mi = 0; mi < 4; mi++)
            af[mi] = *(const bf16x8*)&As[(h & 3) * 2048 +
                                         (mi * 16 + ln15) * 32 + xsel];
        MMAC(bA, af);                                // implicit wait B(h)
        __builtin_amdgcn_sched_barrier(0);
        // odd half-step: buf (h+1)&3, B = bB
        L1BAR();                                     // A(h+1) landed
        if (h + 3 < NT1) stageA((h + 3) & 3, h + 3);
        __builtin_amdgcn_sched_barrier(0);           // pin A before B
        if (h + 2 < NT1) { LOADB(bA, W1T, K1, (h + 2) * 32); }
        #pragma unroll
        for (int mi = 0; mi < 4; mi++)
            af[mi] = *(const bf16x8*)&As[((h + 1) & 3) * 2048 +
                                         (mi * 16 + ln15) * 32 + xsel];
        MMAC(bB, af);                                // implicit wait B(h+1)
        __builtin_amdgcn_sched_barrier(0);
    }

    if constexpr (PATH == 2) {
        // single layer: tanh -> out at leftover slot
        int qmap[8];
        #pragma unroll
        for (int i = 0; i < 8; i++) {
            const int f = idx[i];
            int q = 24;
            for (int l = 0; l < 16; l++)
                if (leftover[l] == f) q = 24 + l;
            qmap[i] = q;
        }
        #pragma unroll
        for (int ni = 0; ni < 8; ni++) {
            const int n = wn + ni * 16 + ln15;
            const float bv = b1[n];
            #pragma unroll
            for (int mi = 0; mi < 4; mi++)
                #pragma unroll
                for (int j = 0; j < 4; j++) {
                    const int r = mi * 16 + kq * 4 + j;
                    const int m = m0 + r;
                    const int b = m >> 3, i = m & 7;
                    out[((size_t)b * 40 + qmap[i]) * 512 + n] =
                        tanhf(acc[mi][ni][j] + bv);
                }
        }
        return;
    }

    // ---- L1 epilogue: relu -> bf16 -> hid LDS (XOR-swizzled chunks) ----
    #pragma unroll
    for (int ni = 0; ni < 8; ni++) {
        const int n  = wn + ni * 16 + ln15;
        const float bv = b1[n];
        const int c8 = n >> 3;
        const int cl = (n & 7) * 2;
        #pragma unroll
        for (int mi = 0; mi < 4; mi++)
            #pragma unroll
            for (int j = 0; j < 4; j++) {
                const int r = mi * 16 + kq * 4 + j;
                float v = acc[mi][ni][j] + bv;
                v = v > 0.f ? v : 0.f;
                *(unsigned short*)((char*)hid + r * 1024 +
                                   ((c8 ^ (r & 7)) * 16) + cl) = f2bf(v);
            }
    }
    #pragma unroll
    for (int mi = 0; mi < 4; mi++)
        #pragma unroll
        for (int ni = 0; ni < 8; ni++)
            acc[mi][ni] = f32x4{0.f, 0.f, 0.f, 0.f};
    LOADB(bA, W2T, 512, 0);
    __syncthreads();                       // hid visible (full drain, once)

    // ---- L2: acc = hid[64,512] @ W2[512,512], A from LDS, no barriers ----
    for (int t2 = 0; t2 < 16; t2 += 2) {
        bf16x8 af[4];
        #pragma unroll
        for (int mi = 0; mi < 4; mi++) {
            const int r = mi * 16 + ln15;
            const int c8 = t2 * 4 + kq;
            af[mi] = *(const bf16x8*)((char*)hid + r * 1024 +
                                      ((c8 ^ (r & 7)) * 16));
        }
        LOADB(bB, W2T, 512, (t2 + 1) * 32);
        MMAC(bA, af);
        #pragma unroll
        for (int mi = 0; mi < 4; mi++) {
            const int r = mi * 16 + ln15;
            const int c8 = (t2 + 1) * 4 + kq;
            af[mi] = *(const bf16x8*)((char*)hid + r * 1024 +
                                      ((c8 ^ (r & 7)) * 16));
        }
        if (t2 + 2 < 16) { LOADB(bA, W2T, 512, (t2 + 2) * 32); }
        MMAC(bB, af);
    }

    // ---- L2 epilogue: +bias -> fp32 out ----
    #pragma unroll
    for (int ni = 0; ni < 8; ni++) {
        const int n  = wn + ni * 16 + ln15;
        const float bv = b2[n];
        #pragma unroll
        for (int mi = 0; mi < 4; mi++)
            #pragma unroll
            for (int j = 0; j < 4; j++) {
                const int r = mi * 16 + kq * 4 + j;
                const int m = m0 + r;
                const int b = m / P, p = m % P;    // P constexpr -> shifts
                out[((size_t)b * 40 + QBASE + p) * 512 + n] =
                    acc[mi][ni][j] + bv;
            }
    }
}

// ---------- fused phase kernel ----------
struct FArgs {
    const unsigned short *fvb, *and_W1T, *and_W2T, *or_W1T, *or_W2T, *not_WT;
    const int *and_pairs, *or_pairs, *not_idx, *leftover;
    const float *and_b1, *and_b2, *or_b1, *or_b2, *not_b;
    float* out;
};

__global__ __launch_bounds__(256, 2) void fused_phase(FArgs a) {
    __shared__ __align__(16) unsigned short As[4 * 64 * 32];   // 16 KB, 4 bufs
    __shared__ __align__(16) unsigned short hid[64 * 512];     // 64 KB
    const int blk = blockIdx.x;
    if (blk < 256)        // and: M=16384 -> 256 blocks of 64 rows
        fused_seg<16, 1024, 0, 0, 0>(a.fvb, a.and_pairs, a.and_W1T, a.and_b1,
                                     a.and_W2T, a.and_b2, a.out, nullptr,
                                     blk, As, hid);
    else if (blk < 384)   // or: M=8192 -> 128 blocks
        fused_seg<8, 1024, 0, 0, 16>(a.fvb, a.or_pairs, a.or_W1T, a.or_b1,
                                     a.or_W2T, a.or_b2, a.out, nullptr,
                                     blk - 256, As, hid);
    else                  // not: M=8192, single layer tanh -> 128 blocks
        fused_seg<8, 512, 1, 2, 24>(a.fvb, a.not_idx, a.not_WT, a.not_b,
                                    nullptr, nullptr, a.out, a.leftover,
                                    blk - 384, As, hid);
}

// ---------- launch ----------
extern "C" void kernel_launch(void* const* d_in, const int* in_sizes, int n_in,
                              void* d_out, int out_size, void* d_ws, size_t ws_size,
                              hipStream_t stream) {
    const float* fv       = (const float*)d_in[0];
    const float* and_W1   = (const float*)d_in[1];
    const float* and_b1   = (const float*)d_in[2];
    const float* and_W2   = (const float*)d_in[3];
    const float* and_b2   = (const float*)d_in[4];
    const float* or_W1    = (const float*)d_in[5];
    const float* or_b1    = (const float*)d_in[6];
    const float* or_W2    = (const float*)d_in[7];
    const float* or_b2    = (const float*)d_in[8];
    const float* not_W    = (const float*)d_in[9];
    const float* not_b    = (const float*)d_in[10];
    const int* not_idx    = (const int*)d_in[11];
    const int* and_pairs  = (const int*)d_in[12];
    const int* or_pairs   = (const int*)d_in[13];
    const int* leftover   = (const int*)d_in[14];
    float* out = (float*)d_out;
    char* ws = (char*)d_ws;

    // ws layout (bytes)
    unsigned short* fvb     = (unsigned short*)(ws);              // 64 MB bf16 fv
    unsigned short* and_W1T = (unsigned short*)(ws + 67108864);   // 1 MB
    unsigned short* or_W1T  = (unsigned short*)(ws + 68157440);   // 1 MB
    unsigned short* and_W2T = (unsigned short*)(ws + 69206016);   // 0.5 MB
    unsigned short* or_W2T  = (unsigned short*)(ws + 69730304);   // 0.5 MB
    unsigned short* not_WT  = (unsigned short*)(ws + 70254592);   // 0.5 MB
    int*            tbl     = (int*)(ws + 70778880);              // 256 B

    SetupArgs sa;
    sa.and_pairs = and_pairs; sa.or_pairs = or_pairs;
    sa.not_idx = not_idx; sa.lidx = leftover; sa.tbl = tbl;
    sa.W[0] = and_W1; sa.WT[0] = and_W1T; sa.K[0] = 1024; sa.N[0] = 512;
    sa.W[1] = or_W1;  sa.WT[1] = or_W1T;  sa.K[1] = 1024; sa.N[1] = 512;
    sa.W[2] = and_W2; sa.WT[2] = and_W2T; sa.K[2] = 512;  sa.N[2] = 512;
    sa.W[3] = or_W2;  sa.WT[3] = or_W2T;  sa.K[3] = 512;  sa.N[3] = 512;
    sa.W[4] = not_W;  sa.WT[4] = not_WT;  sa.K[4] = 512;  sa.N[4] = 512;
    sa.tstart[0] = 0;   sa.tstart[1] = 128; sa.tstart[2] = 256;
    sa.tstart[3] = 320; sa.tstart[4] = 384; sa.tstart[5] = 448;
    setup_kernel<<<dim3(449), dim3(256), 0, stream>>>(sa);

    PrepArgs pa;
    pa.fv = fv; pa.fvb = fvb; pa.tbl = tbl; pa.out = out;
    prep_kernel<<<dim3(16384), dim3(256), 0, stream>>>(pa);

    FArgs fa;
    fa.fvb = fvb;
    fa.and_W1T = and_W1T; fa.and_W2T = and_W2T;
    fa.or_W1T = or_W1T;   fa.or_W2T = or_W2T;   fa.not_WT = not_WT;
    fa.and_pairs = and_pairs; fa.or_pairs = or_pairs; fa.not_idx = not_idx;
    fa.leftover = leftover;
    fa.and_b1 = and_b1; fa.and_b2 = and_b2;
    fa.or_b1 = or_b1;   fa.or_b2 = or_b2;   fa.not_b = not_b;
    fa.out = out;
    fused_phase<<<dim3(512), dim3(256), 0, stream>>>(fa);
}

// Round 8
// 312.177 us; speedup vs baseline: 1.1939x; 1.1939x over previous
//
#include <hip/hip_runtime.h>
#include <hip/hip_bf16.h>
#include <math.h>

// ---------- types ----------
typedef __attribute__((ext_vector_type(8))) __bf16 bf16x8;
typedef __attribute__((ext_vector_type(4))) float f32x4;

// fp32 -> bf16 round-to-nearest-even
__device__ __forceinline__ unsigned short f2bf(float f) {
    union { float f; unsigned u; } v; v.f = f;
    unsigned r = v.u + 0x7fffu + ((v.u >> 16) & 1u);
    return (unsigned short)(r >> 16);
}
// pack two fp32 into one dword of two bf16 (lo, hi)
__device__ __forceinline__ unsigned int pk(float a, float b) {
    union { float f; unsigned u; } x, y; x.f = a; y.f = b;
    unsigned ra = (x.u + 0x7fffu + ((x.u >> 16) & 1u)) >> 16;
    unsigned rb = (y.u + 0x7fffu + ((y.u >> 16) & 1u)) & 0xffff0000u;
    return ra | rb;
}

// async global->LDS, 16 B per lane; LDS dest = wave-uniform base + lane*16
__device__ __forceinline__ void gl2lds16(const unsigned short* g, unsigned short* l) {
    __builtin_amdgcn_global_load_lds(
        (const __attribute__((address_space(1))) unsigned int*)(g),
        (__attribute__((address_space(3))) unsigned int*)(l), 16, 0, 0);
}

// ---------- setup kernel ----------
// block 0: packed membership table tbl[f] = used | (lslot+1)<<8
// blocks 1..448: weight convert to MFMA FRAGMENT ORDER:
//   WTf[kt][cg][lane][e]  (kt = k/32 tile, cg = col/16 group)
//   lane l, elem e -> W[kt*32 + (l>>4)*8 + e][cg*16 + (l&15)]
// so a B-fragment load in the GEMM is base + lane*16: 64 lanes x 16 B
// CONTIGUOUS (1 KB) -- fully coalesced.  (Round-7 lesson: the row-major
// WT[n][k] layout made every B load a 16-way cache-line split gather;
// ~144 split line-requests per wave per half-step was the real ceiling.)
struct SetupArgs {
    const int *and_pairs, *or_pairs, *not_idx, *lidx;
    int* tbl;                       // 64 ints
    const float* W[5];
    unsigned short* WT[5];
    int K[5], N[5];
    int tstart[6];
};

__global__ __launch_bounds__(256) void setup_kernel(SetupArgs a) {
    __shared__ float tile[64][65];
    const int blk = blockIdx.x;
    const int tid = threadIdx.x;

    if (blk == 0) {
        if (tid < 64) {
            const int f = tid;
            int u = 0;
            for (int i = 0; i < 32; i++) u |= (a.and_pairs[i] == f);
            for (int i = 0; i < 16; i++) u |= (a.or_pairs[i] == f);
            int isnot = 0;
            for (int i = 0; i < 8; i++)  isnot |= (a.not_idx[i] == f);
            int ls = -1;
            for (int l = 0; l < 16; l++) if (a.lidx[l] == f) ls = l;
            if (isnot) ls = -1;          // tanh epilogue writes these slots
            a.tbl[f] = (u | isnot) | ((ls + 1) << 8);
        }
        return;
    }

    const int bx = blk - 1;
    int m = 0;
    while (bx >= a.tstart[m + 1]) m++;
    const float* src = a.W[m];
    unsigned short* dst = a.WT[m];
    const int K = a.K[m], N = a.N[m];
    const int t = bx - a.tstart[m];
    const int ntn = N >> 6;
    const int tk = t / ntn, tn = t % ntn;
    const int c = tid & 63, r0 = tid >> 6;
    // tile[r][c] = W[k = tk*64+r][n = tn*64+c]
    #pragma unroll
    for (int r = r0; r < 64; r += 4)
        tile[r][c] = src[(size_t)(tk * 64 + r) * N + tn * 64 + c];
    __syncthreads();
    // emit 8 fragments (2 kt x 4 cg), 64 lanes x 16 B each, coalesced dst
    const int l = tid & 63;
    #pragma unroll
    for (int fi = tid >> 6; fi < 8; fi += 4) {
        const int ktl = fi & 1, cgl = fi >> 1;
        const int kt = tk * 2 + ktl, cg = tn * 4 + cgl;
        const int kb = ktl * 32 + (l >> 4) * 8;
        const int nb = cgl * 16 + (l & 15);
        uint4 o;
        o.x = pk(tile[kb + 0][nb], tile[kb + 1][nb]);
        o.y = pk(tile[kb + 2][nb], tile[kb + 3][nb]);
        o.z = pk(tile[kb + 4][nb], tile[kb + 5][nb]);
        o.w = pk(tile[kb + 6][nb], tile[kb + 7][nb]);
        ((uint4*)dst)[((size_t)kt * 32 + cg) * 64 + l] = o;
    }
}

// ---------- prep kernel: pure streaming, no LDS, no syncs ----------
struct PrepArgs {
    const float* fv;
    unsigned short* fvb;
    const int* tbl;
    float* out;
};

__global__ __launch_bounds__(256) void prep_kernel(PrepArgs a) {
    const int t = blockIdx.x * 256 + threadIdx.x;   // 8 consecutive floats
    const size_t e = (size_t)t * 8;
    const int c = (int)(e & 511);
    const int f = (int)((e >> 9) & 63);
    const int b = (int)(e >> 15);
    const float4 v0 = *(const float4*)(a.fv + e);
    const float4 v1 = *(const float4*)(a.fv + e + 4);
    const int tb = a.tbl[f];                        // wave-uniform
    const int u  = tb & 0xff;
    const int ls = (tb >> 8) - 1;
    if (u) {
        uint4 o;
        o.x = pk(v0.x, v0.y); o.y = pk(v0.z, v0.w);
        o.z = pk(v1.x, v1.y); o.w = pk(v1.z, v1.w);
        ((uint4*)a.fvb)[t] = o;
    }
    if (ls >= 0) {
        float* d = a.out + ((size_t)b * 40 + 24 + ls) * 512 + c;
        *(float4*)(d)     = v0;
        *(float4*)(d + 4) = v1;
    }
}

// ---------- fused two-layer GEMM segment ----------
// Block: BM=64 rows x ALL 512 cols; L2 stage's A (=hid) is this block's L1
// output -> full MLP fused, hid lives in LDS only. 4 waves, wave w owns cols
// [w*128, +128): acc[4][8].
// A: global_load_lds, 4 buffers, staged 2 STEPS AHEAD.
// B: per-lane direct global->reg 16B fragment loads, FRAGMENT-ORDERED
//    layout -> each load is 64 lanes x 16 B contiguous (coalesced).
// L1 K-loop, counted waits (T4): barrier = s_waitcnt vmcnt(9) lgkmcnt(0);
// s_barrier, with sched_barrier(0)-pinned VMEM issue order
//   [A0, A1, B0 | A2, B1 | A3, B2 | ...]
// (proof in round-6/7 notes: A(s) is drained by vmcnt(9) at s=0 and by the
// previous MMAC's implicit wait on B(s-1) afterwards; WAR on the 4 A-bufs
// covered by lgkmcnt(0)+barrier; sched_barrier(0) after each MMAC pins the
// MFMA cluster -- rule 18).
// hid LDS [64][512] bf16, 16B-chunk XOR swizzle -> L2-stage reads 2-way max.
// PATH 0: relu->hid(LDS)->L2->out fp32 (+bias), rows m=b*P+p, q=QBASE+p
// PATH 2: single layer, tanh->out, rows m=b*8+i, q=qmap[i]
// SRCM 0: A row m = concat(fvb[b,idx[2p]], fvb[b,idx[2p+1]]), K1=1024
// SRCM 1: A row m = fvb[b, idx[i]], K1=512
#define LOADB(DST, WTP, KD, K0)                                              \
    _Pragma("unroll") for (int ni = 0; ni < 8; ni++)                         \
        DST[ni] = *(const bf16x8*)((WTP) +                                   \
            ((((size_t)(K0) >> 5) * 32 + cg0 + ni) << 9) + (lane << 3));

#define MMAC(BF, AF)                                                         \
    _Pragma("unroll") for (int mi = 0; mi < 4; mi++)                         \
    _Pragma("unroll") for (int ni = 0; ni < 8; ni++)                         \
        acc[mi][ni] = __builtin_amdgcn_mfma_f32_16x16x32_bf16(               \
            AF[mi], BF[ni], acc[mi][ni], 0, 0, 0);

#define L1BAR()                                                              \
    asm volatile("s_waitcnt vmcnt(9) lgkmcnt(0)" ::: "memory");              \
    asm volatile("s_barrier" ::: "memory");

template <int P, int K1, int SRCM, int PATH, int QBASE>
__device__ __forceinline__ void fused_seg(
    const unsigned short* __restrict__ A,
    const int* __restrict__ idx,
    const unsigned short* __restrict__ W1T,
    const float* __restrict__ b1,
    const unsigned short* __restrict__ W2T,
    const float* __restrict__ b2,
    float* __restrict__ out,
    const int* __restrict__ leftover,
    int local,
    unsigned short* As, unsigned short* hid) {

    const int tid  = threadIdx.x;
    const int lane = tid & 63, w = tid >> 6;
    const int ln15 = lane & 15;
    const int kq   = lane >> 4;          // k-chunk quad 0..3
    const int wn   = w * 128;            // wave's col base
    const int cg0  = w * 8;              // wave's col-group base (fragments)
    const int m0   = local * 64;         // block's row base

    // --- A staging: wave w stages rows [w*16, +16); lane l -> row l>>2,
    // swizzled source k-chunk ((l&3)^((l>>2)&3))*8 shorts (16 B)
    const int skin = ((lane & 3) ^ ((lane >> 2) & 3)) * 8;
    const unsigned short *ar0, *ar1;
    {
        const int m = m0 + w * 16 + (lane >> 2);
        if constexpr (SRCM == 0) {
            const int b = m / P, p = m % P;
            ar0 = A + ((size_t)b * 64 + idx[2 * p]) * 512;
            ar1 = A + ((size_t)b * 64 + idx[2 * p + 1]) * 512;
        } else {
            const int b = m >> 3, i = m & 7;
            ar0 = A + ((size_t)b * 64 + idx[i]) * 512;
            ar1 = ar0;
        }
    }
    auto stageA = [&](int buf, int t) {
        const int k0 = t * 32;
        const unsigned short* src;
        if constexpr (SRCM == 0)
            src = (k0 >= 512 ? ar1 + (k0 - 512) : ar0 + k0) + skin;
        else
            src = ar0 + k0 + skin;
        gl2lds16(src, &As[buf * 2048 + w * 512]);
    };
    const int xsel = (kq ^ (lane & 3)) * 8;   // frag-read chunk slot

    f32x4 acc[4][8];
    #pragma unroll
    for (int mi = 0; mi < 4; mi++)
        #pragma unroll
        for (int ni = 0; ni < 8; ni++)
            acc[mi][ni] = f32x4{0.f, 0.f, 0.f, 0.f};

    bf16x8 bA[8], bB[8];

    // ---- L1: acc = A[64,K1] @ W1[K1,512] ----
    constexpr int NT1 = K1 / 32;   // even
    stageA(0, 0);                  // A0: MUST be oldest in flight
    stageA(1, 1);                  // A1
    __builtin_amdgcn_sched_barrier(0);   // pin A0,A1 before B0
    LOADB(bA, W1T, K1, 0);         // B0 x8; outstanding = [A0,A1,B0x8] = 10

    for (int h = 0; h < NT1; h += 2) {
        // even half-step: buf h&3, B = bA
        L1BAR();                                     // A(h) landed
        if (h + 2 < NT1) stageA((h + 2) & 3, h + 2); // A(h+2), 2-deep
        __builtin_amdgcn_sched_barrier(0);           // pin A before B
        LOADB(bB, W1T, K1, (h + 1) * 32);            // B(h+1)
        bf16x8 af[4];
        #pragma unroll
        for (int mi = 0; mi < 4; mi++)
            af[mi] = *(const bf16x8*)&As[(h & 3) * 2048 +
                                         (mi * 16 + ln15) * 32 + xsel];
        MMAC(bA, af);                                // implicit wait B(h)
        __builtin_amdgcn_sched_barrier(0);
        // odd half-step: buf (h+1)&3, B = bB
        L1BAR();                                     // A(h+1) landed
        if (h + 3 < NT1) stageA((h + 3) & 3, h + 3);
        __builtin_amdgcn_sched_barrier(0);           // pin A before B
        if (h + 2 < NT1) { LOADB(bA, W1T, K1, (h + 2) * 32); }
        #pragma unroll
        for (int mi = 0; mi < 4; mi++)
            af[mi] = *(const bf16x8*)&As[((h + 1) & 3) * 2048 +
                                         (mi * 16 + ln15) * 32 + xsel];
        MMAC(bB, af);                                // implicit wait B(h+1)
        __builtin_amdgcn_sched_barrier(0);
    }

    if constexpr (PATH == 2) {
        // single layer: tanh -> out at leftover slot
        int qmap[8];
        #pragma unroll
        for (int i = 0; i < 8; i++) {
            const int f = idx[i];
            int q = 24;
            for (int l = 0; l < 16; l++)
                if (leftover[l] == f) q = 24 + l;
            qmap[i] = q;
        }
        #pragma unroll
        for (int ni = 0; ni < 8; ni++) {
            const int n = wn + ni * 16 + ln15;
            const float bv = b1[n];
            #pragma unroll
            for (int mi = 0; mi < 4; mi++)
                #pragma unroll
                for (int j = 0; j < 4; j++) {
                    const int r = mi * 16 + kq * 4 + j;
                    const int m = m0 + r;
                    const int b = m >> 3, i = m & 7;
                    out[((size_t)b * 40 + qmap[i]) * 512 + n] =
                        tanhf(acc[mi][ni][j] + bv);
                }
        }
        return;
    }

    // ---- L1 epilogue: relu -> bf16 -> hid LDS (XOR-swizzled chunks) ----
    #pragma unroll
    for (int ni = 0; ni < 8; ni++) {
        const int n  = wn + ni * 16 + ln15;
        const float bv = b1[n];
        const int c8 = n >> 3;
        const int cl = (n & 7) * 2;
        #pragma unroll
        for (int mi = 0; mi < 4; mi++)
            #pragma unroll
            for (int j = 0; j < 4; j++) {
                const int r = mi * 16 + kq * 4 + j;
                float v = acc[mi][ni][j] + bv;
                v = v > 0.f ? v : 0.f;
                *(unsigned short*)((char*)hid + r * 1024 +
                                   ((c8 ^ (r & 7)) * 16) + cl) = f2bf(v);
            }
    }
    #pragma unroll
    for (int mi = 0; mi < 4; mi++)
        #pragma unroll
        for (int ni = 0; ni < 8; ni++)
            acc[mi][ni] = f32x4{0.f, 0.f, 0.f, 0.f};
    LOADB(bA, W2T, 512, 0);
    __syncthreads();                       // hid visible (full drain, once)

    // ---- L2: acc = hid[64,512] @ W2[512,512], A from LDS, no barriers ----
    for (int t2 = 0; t2 < 16; t2 += 2) {
        bf16x8 af[4];
        #pragma unroll
        for (int mi = 0; mi < 4; mi++) {
            const int r = mi * 16 + ln15;
            const int c8 = t2 * 4 + kq;
            af[mi] = *(const bf16x8*)((char*)hid + r * 1024 +
                                      ((c8 ^ (r & 7)) * 16));
        }
        LOADB(bB, W2T, 512, (t2 + 1) * 32);
        MMAC(bA, af);
        #pragma unroll
        for (int mi = 0; mi < 4; mi++) {
            const int r = mi * 16 + ln15;
            const int c8 = (t2 + 1) * 4 + kq;
            af[mi] = *(const bf16x8*)((char*)hid + r * 1024 +
                                      ((c8 ^ (r & 7)) * 16));
        }
        if (t2 + 2 < 16) { LOADB(bA, W2T, 512, (t2 + 2) * 32); }
        MMAC(bB, af);
    }

    // ---- L2 epilogue: +bias -> fp32 out ----
    #pragma unroll
    for (int ni = 0; ni < 8; ni++) {
        const int n  = wn + ni * 16 + ln15;
        const float bv = b2[n];
        #pragma unroll
        for (int mi = 0; mi < 4; mi++)
            #pragma unroll
            for (int j = 0; j < 4; j++) {
                const int r = mi * 16 + kq * 4 + j;
                const int m = m0 + r;
                const int b = m / P, p = m % P;    // P constexpr -> shifts
                out[((size_t)b * 40 + QBASE + p) * 512 + n] =
                    acc[mi][ni][j] + bv;
            }
    }
}

// ---------- fused phase kernel ----------
struct FArgs {
    const unsigned short *fvb, *and_W1T, *and_W2T, *or_W1T, *or_W2T, *not_WT;
    const int *and_pairs, *or_pairs, *not_idx, *leftover;
    const float *and_b1, *and_b2, *or_b1, *or_b2, *not_b;
    float* out;
};

__global__ __launch_bounds__(256, 2) void fused_phase(FArgs a) {
    __shared__ __align__(16) unsigned short As[4 * 64 * 32];   // 16 KB, 4 bufs
    __shared__ __align__(16) unsigned short hid[64 * 512];     // 64 KB
    const int blk = blockIdx.x;
    if (blk < 256)        // and: M=16384 -> 256 blocks of 64 rows
        fused_seg<16, 1024, 0, 0, 0>(a.fvb, a.and_pairs, a.and_W1T, a.and_b1,
                                     a.and_W2T, a.and_b2, a.out, nullptr,
                                     blk, As, hid);
    else if (blk < 384)   // or: M=8192 -> 128 blocks
        fused_seg<8, 1024, 0, 0, 16>(a.fvb, a.or_pairs, a.or_W1T, a.or_b1,
                                     a.or_W2T, a.or_b2, a.out, nullptr,
                                     blk - 256, As, hid);
    else                  // not: M=8192, single layer tanh -> 128 blocks
        fused_seg<8, 512, 1, 2, 24>(a.fvb, a.not_idx, a.not_WT, a.not_b,
                                    nullptr, nullptr, a.out, a.leftover,
                                    blk - 384, As, hid);
}

// ---------- launch ----------
extern "C" void kernel_launch(void* const* d_in, const int* in_sizes, int n_in,
                              void* d_out, int out_size, void* d_ws, size_t ws_size,
                              hipStream_t stream) {
    const float* fv       = (const float*)d_in[0];
    const float* and_W1   = (const float*)d_in[1];
    const float* and_b1   = (const float*)d_in[2];
    const float* and_W2   = (const float*)d_in[3];
    const float* and_b2   = (const float*)d_in[4];
    const float* or_W1    = (const float*)d_in[5];
    const float* or_b1    = (const float*)d_in[6];
    const float* or_W2    = (const float*)d_in[7];
    const float* or_b2    = (const float*)d_in[8];
    const float* not_W    = (const float*)d_in[9];
    const float* not_b    = (const float*)d_in[10];
    const int* not_idx    = (const int*)d_in[11];
    const int* and_pairs  = (const int*)d_in[12];
    const int* or_pairs   = (const int*)d_in[13];
    const int* leftover   = (const int*)d_in[14];
    float* out = (float*)d_out;
    char* ws = (char*)d_ws;

    // ws layout (bytes)
    unsigned short* fvb     = (unsigned short*)(ws);              // 64 MB bf16 fv
    unsigned short* and_W1T = (unsigned short*)(ws + 67108864);   // 1 MB
    unsigned short* or_W1T  = (unsigned short*)(ws + 68157440);   // 1 MB
    unsigned short* and_W2T = (unsigned short*)(ws + 69206016);   // 0.5 MB
    unsigned short* or_W2T  = (unsigned short*)(ws + 69730304);   // 0.5 MB
    unsigned short* not_WT  = (unsigned short*)(ws + 70254592);   // 0.5 MB
    int*            tbl     = (int*)(ws + 70778880);              // 256 B

    SetupArgs sa;
    sa.and_pairs = and_pairs; sa.or_pairs = or_pairs;
    sa.not_idx = not_idx; sa.lidx = leftover; sa.tbl = tbl;
    sa.W[0] = and_W1; sa.WT[0] = and_W1T; sa.K[0] = 1024; sa.N[0] = 512;
    sa.W[1] = or_W1;  sa.WT[1] = or_W1T;  sa.K[1] = 1024; sa.N[1] = 512;
    sa.W[2] = and_W2; sa.WT[2] = and_W2T; sa.K[2] = 512;  sa.N[2] = 512;
    sa.W[3] = or_W2;  sa.WT[3] = or_W2T;  sa.K[3] = 512;  sa.N[3] = 512;
    sa.W[4] = not_W;  sa.WT[4] = not_WT;  sa.K[4] = 512;  sa.N[4] = 512;
    sa.tstart[0] = 0;   sa.tstart[1] = 128; sa.tstart[2] = 256;
    sa.tstart[3] = 320; sa.tstart[4] = 384; sa.tstart[5] = 448;
    setup_kernel<<<dim3(449), dim3(256), 0, stream>>>(sa);

    PrepArgs pa;
    pa.fv = fv; pa.fvb = fvb; pa.tbl = tbl; pa.out = out;
    prep_kernel<<<dim3(16384), dim3(256), 0, stream>>>(pa);

    FArgs fa;
    fa.fvb = fvb;
    fa.and_W1T = and_W1T; fa.and_W2T = and_W2T;
    fa.or_W1T = or_W1T;   fa.or_W2T = or_W2T;   fa.not_WT = not_WT;
    fa.and_pairs = and_pairs; fa.or_pairs = or_pairs; fa.not_idx = not_idx;
    fa.leftover = leftover;
    fa.and_b1 = and_b1; fa.and_b2 = and_b2;
    fa.or_b1 = or_b1;   fa.or_b2 = or_b2;   fa.not_b = not_b;
    fa.out = out;
    fused_phase<<<dim3(512), dim3(256), 0, stream>>>(fa);
}

// Round 9
// 302.892 us; speedup vs baseline: 1.2305x; 1.0307x over previous
//
#include <hip/hip_runtime.h>
#include <hip/hip_bf16.h>
#include <math.h>

// ---------- types ----------
typedef __attribute__((ext_vector_type(8))) __bf16 bf16x8;
typedef __attribute__((ext_vector_type(4))) float f32x4;

// fp32 -> bf16 round-to-nearest-even
__device__ __forceinline__ unsigned short f2bf(float f) {
    union { float f; unsigned u; } v; v.f = f;
    unsigned r = v.u + 0x7fffu + ((v.u >> 16) & 1u);
    return (unsigned short)(r >> 16);
}
// pack two fp32 into one dword of two bf16 (lo, hi)
__device__ __forceinline__ unsigned int pk(float a, float b) {
    union { float f; unsigned u; } x, y; x.f = a; y.f = b;
    unsigned ra = (x.u + 0x7fffu + ((x.u >> 16) & 1u)) >> 16;
    unsigned rb = (y.u + 0x7fffu + ((y.u >> 16) & 1u)) & 0xffff0000u;
    return ra | rb;
}

// async global->LDS, 16 B per lane; LDS dest = wave-uniform base + lane*16
__device__ __forceinline__ void gl2lds16(const unsigned short* g, unsigned short* l) {
    __builtin_amdgcn_global_load_lds(
        (const __attribute__((address_space(1))) unsigned int*)(g),
        (__attribute__((address_space(3))) unsigned int*)(l), 16, 0, 0);
}

// ---------- prep kernel (merged with weight setup) ----------
// blocks [0,448): weight convert to MFMA FRAGMENT ORDER:
//   WTf[kt][cg][lane][e]  (kt=k/32 tile, cg=col/16 group)
//   lane l, elem e -> W[kt*32 + (l>>4)*8 + e][cg*16 + (l&15)]
//   -> B-fragment load in GEMM = base + lane*16: 64 lanes x 16 B CONTIGUOUS.
// blocks [448, 448+16384): fv streaming.  One wave = one field row (512
// floats); membership computed per-wave via 4 ballots (no table, no extra
// kernel, no tbl global round-trip):
//   lane<32 checks and_pairs[lane], lane<16 or_pairs, lane<8 not_idx,
//   lane<16 leftover -> wave-uniform ballot masks.
struct PrepArgs {
    const float* fv;
    unsigned short* fvb;
    const int *and_pairs, *or_pairs, *not_idx, *lidx;
    float* out;
    const float* W[5];
    unsigned short* WT[5];
    int N[5];
    int tstart[6];
};

__global__ __launch_bounds__(256) void prep_kernel(PrepArgs a) {
    __shared__ float tile[64][65];
    const int blk = blockIdx.x;
    const int tid = threadIdx.x;

    if (blk < 448) {
        int m = 0;
        while (blk >= a.tstart[m + 1]) m++;
        const float* src = a.W[m];
        unsigned short* dst = a.WT[m];
        const int N = a.N[m];
        const int t = blk - a.tstart[m];
        const int ntn = N >> 6;
        const int tk = t / ntn, tn = t % ntn;
        const int c = tid & 63, r0 = tid >> 6;
        #pragma unroll
        for (int r = r0; r < 64; r += 4)
            tile[r][c] = src[(size_t)(tk * 64 + r) * N + tn * 64 + c];
        __syncthreads();
        const int l = tid & 63;
        #pragma unroll
        for (int fi = tid >> 6; fi < 8; fi += 4) {
            const int ktl = fi & 1, cgl = fi >> 1;
            const int kt = tk * 2 + ktl, cg = tn * 4 + cgl;
            const int kb = ktl * 32 + (l >> 4) * 8;
            const int nb = cgl * 16 + (l & 15);
            uint4 o;
            o.x = pk(tile[kb + 0][nb], tile[kb + 1][nb]);
            o.y = pk(tile[kb + 2][nb], tile[kb + 3][nb]);
            o.z = pk(tile[kb + 4][nb], tile[kb + 5][nb]);
            o.w = pk(tile[kb + 6][nb], tile[kb + 7][nb]);
            ((uint4*)dst)[((size_t)kt * 32 + cg) * 64 + l] = o;
        }
        return;
    }

    const int t = (blk - 448) * 256 + tid;   // 8 consecutive floats
    const int lane = tid & 63;
    const size_t e = (size_t)t * 8;
    const int c = (int)(e & 511);
    const int f = (int)((e >> 9) & 63);
    const int b = (int)(e >> 15);
    const float4 v0 = *(const float4*)(a.fv + e);
    const float4 v1 = *(const float4*)(a.fv + e + 4);
    const int am = (lane < 32) ? a.and_pairs[lane] : -1;
    const int om = (lane < 16) ? a.or_pairs[lane]  : -1;
    const int nm = (lane <  8) ? a.not_idx[lane]   : -1;
    const int lm = (lane < 16) ? a.lidx[lane]      : -1;
    const unsigned long long bn = __ballot(nm == f);
    const unsigned long long bu = __ballot(am == f) | __ballot(om == f) | bn;
    const unsigned long long bl = __ballot(lm == f);
    if (bu) {
        uint4 o;
        o.x = pk(v0.x, v0.y); o.y = pk(v0.z, v0.w);
        o.z = pk(v1.x, v1.y); o.w = pk(v1.z, v1.w);
        ((uint4*)a.fvb)[t] = o;
    }
    if (bl && !bn) {   // leftover passthrough (not-fields written by tanh GEMM)
        const int ls = (int)__builtin_ctzll(bl);
        float* d = a.out + ((size_t)b * 40 + 24 + ls) * 512 + c;
        *(float4*)(d)     = v0;
        *(float4*)(d + 4) = v1;
    }
}

// ---------- fused two-layer GEMM segment ----------
// Block: BM=64 rows x ALL 512 cols, 8 WAVES, wave owns 64 cols: acc[4][4].
// Round-8 lesson: the 4-wave/128-col variant was register-capped at
// 2 waves/SIMD (128V + 128 AGPR acc).  This variant halves per-wave state
// (64 AGPR acc + single-buffered bA[4] = ~110 regs) -> 4 waves/SIMD via
// __launch_bounds__(512,4); LDS 80 KB -> 2 blocks/CU, grid 512 = 1 epoch.
// A: global_load_lds, 4 buffers, waves 0..3 stage (1 instr each), 2-ahead.
// B: single-buffered, issued at the top of each half-step; the MMAC's
//    compiler-inserted vmcnt wait eats B's L2 latency -- hidden by 4-way TLP.
// Issue order per step (sched_barrier-pinned): B(h) FIRST, then A(h+2), so
// the MMAC's B(h)-wait retires A(h) (1 step cover) but leaves A(h+1),A(h+2)
// in flight.  L1BAR = s_waitcnt vmcnt(1) lgkmcnt(0); s_barrier:
//   h=0: outstanding [A0,A1] -> vmcnt(1) retires A0.  Steady: A(h) already
//   retired by step h-1's B-wait; vmcnt(1) is a no-op.  Non-staging waves
//   (w>=4): <=1 outstanding, no-op; A-visibility comes from the barrier
//   (each staging wave proved its A before arriving).  WAR on the 4 bufs:
//   readers of buf (h+2)&3 ran at h-2 and retired before barrier h-1.
// hid LDS [64][512] bf16, 16B-chunk XOR swizzle -> L2-stage reads 2-way max.
// PATH 0: relu->hid(LDS)->L2->out fp32 (+bias), rows m=b*P+p, q=QBASE+p
// PATH 2: single layer, tanh->out, rows m=b*8+i, q=qmap[i]
// SRCM 0: A row m = concat(fvb[b,idx[2p]], fvb[b,idx[2p+1]]), K1=1024
// SRCM 1: A row m = fvb[b, idx[i]], K1=512
#define LOADB(DST, WTP, K0)                                                  \
    _Pragma("unroll") for (int ni = 0; ni < 4; ni++)                         \
        DST[ni] = *(const bf16x8*)((WTP) +                                   \
            ((((size_t)(K0) >> 5) * 32 + cg0 + ni) << 9) + (lane << 3));

#define MMAC(BF, AF)                                                         \
    _Pragma("unroll") for (int mi = 0; mi < 4; mi++)                         \
    _Pragma("unroll") for (int ni = 0; ni < 4; ni++)                         \
        acc[mi][ni] = __builtin_amdgcn_mfma_f32_16x16x32_bf16(               \
            AF[mi], BF[ni], acc[mi][ni], 0, 0, 0);

template <int P, int K1, int SRCM, int PATH, int QBASE>
__device__ __forceinline__ void fused_seg(
    const unsigned short* __restrict__ A,
    const int* __restrict__ idx,
    const unsigned short* __restrict__ W1T,
    const float* __restrict__ b1,
    const unsigned short* __restrict__ W2T,
    const float* __restrict__ b2,
    float* __restrict__ out,
    const int* __restrict__ leftover,
    int local,
    unsigned short* As, unsigned short* hid) {

    const int tid  = threadIdx.x;
    const int lane = tid & 63, w = tid >> 6;      // 8 waves
    const int ln15 = lane & 15;
    const int kq   = lane >> 4;                   // k-chunk quad 0..3
    const int wn   = w * 64;                      // wave's col base
    const int cg0  = w * 4;                       // wave's col-group base
    const int m0   = local * 64;                  // block's row base

    // --- A staging (waves 0..3 only): wave w stages rows [w*16,+16);
    // lane l -> row l>>2, swizzled source k-chunk ((l&3)^((l>>2)&3))
    const int skin = ((lane & 3) ^ ((lane >> 2) & 3)) * 8;
    const unsigned short *ar0, *ar1;
    {
        const int m = m0 + (w & 3) * 16 + (lane >> 2);
        if constexpr (SRCM == 0) {
            const int b = m / P, p = m % P;
            ar0 = A + ((size_t)b * 64 + idx[2 * p]) * 512;
            ar1 = A + ((size_t)b * 64 + idx[2 * p + 1]) * 512;
        } else {
            const int b = m >> 3, i = m & 7;
            ar0 = A + ((size_t)b * 64 + idx[i]) * 512;
            ar1 = ar0;
        }
    }
    auto stageA = [&](int buf, int t) {
        const int k0 = t * 32;
        const unsigned short* src;
        if constexpr (SRCM == 0)
            src = (k0 >= 512 ? ar1 + (k0 - 512) : ar0 + k0) + skin;
        else
            src = ar0 + k0 + skin;
        gl2lds16(src, &As[buf * 2048 + (w & 3) * 512]);
    };
    const int xsel = (kq ^ (lane & 3)) * 8;   // frag-read chunk slot

    f32x4 acc[4][4];
    #pragma unroll
    for (int mi = 0; mi < 4; mi++)
        #pragma unroll
        for (int ni = 0; ni < 4; ni++)
            acc[mi][ni] = f32x4{0.f, 0.f, 0.f, 0.f};

    bf16x8 bA[4];

    // ---- L1: acc = A[64,K1] @ W1[K1,512] ----
    constexpr int NT1 = K1 / 32;
    if (w < 4) { stageA(0, 0); stageA(1, 1); }
    __builtin_amdgcn_sched_barrier(0);

    for (int h = 0; h < NT1; h++) {
        asm volatile("s_waitcnt vmcnt(1) lgkmcnt(0)" ::: "memory");
        asm volatile("s_barrier" ::: "memory");
        LOADB(bA, W1T, h * 32);                       // B(h) first
        __builtin_amdgcn_sched_barrier(0);            // pin B before A-stage
        if (w < 4 && h + 2 < NT1) stageA((h + 2) & 3, h + 2);
        __builtin_amdgcn_sched_barrier(0);
        bf16x8 af[4];
        #pragma unroll
        for (int mi = 0; mi < 4; mi++)
            af[mi] = *(const bf16x8*)&As[(h & 3) * 2048 +
                                         (mi * 16 + ln15) * 32 + xsel];
        MMAC(bA, af);                                 // waits B(h); A(h+1..2) live
        __builtin_amdgcn_sched_barrier(0);
    }

    if constexpr (PATH == 2) {
        // single layer: tanh -> out at leftover slot
        int qmap[8];
        #pragma unroll
        for (int i = 0; i < 8; i++) {
            const int f = idx[i];
            int q = 24;
            for (int l = 0; l < 16; l++)
                if (leftover[l] == f) q = 24 + l;
            qmap[i] = q;
        }
        #pragma unroll
        for (int ni = 0; ni < 4; ni++) {
            const int n = wn + ni * 16 + ln15;
            const float bv = b1[n];
            #pragma unroll
            for (int mi = 0; mi < 4; mi++)
                #pragma unroll
                for (int j = 0; j < 4; j++) {
                    const int r = mi * 16 + kq * 4 + j;
                    const int m = m0 + r;
                    const int b = m >> 3, i = m & 7;
                    out[((size_t)b * 40 + qmap[i]) * 512 + n] =
                        tanhf(acc[mi][ni][j] + bv);
                }
        }
        return;
    }

    // ---- L1 epilogue: relu -> bf16 -> hid LDS (XOR-swizzled chunks) ----
    #pragma unroll
    for (int ni = 0; ni < 4; ni++) {
        const int n  = wn + ni * 16 + ln15;
        const float bv = b1[n];
        const int c8 = n >> 3;
        const int cl = (n & 7) * 2;
        #pragma unroll
        for (int mi = 0; mi < 4; mi++)
            #pragma unroll
            for (int j = 0; j < 4; j++) {
                const int r = mi * 16 + kq * 4 + j;
                float v = acc[mi][ni][j] + bv;
                v = v > 0.f ? v : 0.f;
                *(unsigned short*)((char*)hid + r * 1024 +
                                   ((c8 ^ (r & 7)) * 16) + cl) = f2bf(v);
            }
    }
    #pragma unroll
    for (int mi = 0; mi < 4; mi++)
        #pragma unroll
        for (int ni = 0; ni < 4; ni++)
            acc[mi][ni] = f32x4{0.f, 0.f, 0.f, 0.f};
    __syncthreads();                       // hid visible (full drain, once)

    // ---- L2: acc = hid[64,512] @ W2[512,512], A from LDS, no barriers ----
    for (int t2 = 0; t2 < 16; t2++) {
        LOADB(bA, W2T, t2 * 32);
        bf16x8 af[4];
        #pragma unroll
        for (int mi = 0; mi < 4; mi++) {
            const int r = mi * 16 + ln15;
            const int c8 = t2 * 4 + kq;
            af[mi] = *(const bf16x8*)((char*)hid + r * 1024 +
                                      ((c8 ^ (r & 7)) * 16));
        }
        MMAC(bA, af);
    }

    // ---- L2 epilogue: +bias -> fp32 out ----
    #pragma unroll
    for (int ni = 0; ni < 4; ni++) {
        const int n  = wn + ni * 16 + ln15;
        const float bv = b2[n];
        #pragma unroll
        for (int mi = 0; mi < 4; mi++)
            #pragma unroll
            for (int j = 0; j < 4; j++) {
                const int r = mi * 16 + kq * 4 + j;
                const int m = m0 + r;
                const int b = m / P, p = m % P;    // P constexpr -> shifts
                out[((size_t)b * 40 + QBASE + p) * 512 + n] =
                    acc[mi][ni][j] + bv;
            }
    }
}

// ---------- fused phase kernel ----------
struct FArgs {
    const unsigned short *fvb, *and_W1T, *and_W2T, *or_W1T, *or_W2T, *not_WT;
    const int *and_pairs, *or_pairs, *not_idx, *leftover;
    const float *and_b1, *and_b2, *or_b1, *or_b2, *not_b;
    float* out;
};

__global__ __launch_bounds__(512, 4) void fused_phase(FArgs a) {
    __shared__ __align__(16) unsigned short As[4 * 64 * 32];   // 16 KB, 4 bufs
    __shared__ __align__(16) unsigned short hid[64 * 512];     // 64 KB
    const int blk = blockIdx.x;
    if (blk < 256)        // and: M=16384 -> 256 blocks of 64 rows
        fused_seg<16, 1024, 0, 0, 0>(a.fvb, a.and_pairs, a.and_W1T, a.and_b1,
                                     a.and_W2T, a.and_b2, a.out, nullptr,
                                     blk, As, hid);
    else if (blk < 384)   // or: M=8192 -> 128 blocks
        fused_seg<8, 1024, 0, 0, 16>(a.fvb, a.or_pairs, a.or_W1T, a.or_b1,
                                     a.or_W2T, a.or_b2, a.out, nullptr,
                                     blk - 256, As, hid);
    else                  // not: M=8192, single layer tanh -> 128 blocks
        fused_seg<8, 512, 1, 2, 24>(a.fvb, a.not_idx, a.not_WT, a.not_b,
                                    nullptr, nullptr, a.out, a.leftover,
                                    blk - 384, As, hid);
}

// ---------- launch ----------
extern "C" void kernel_launch(void* const* d_in, const int* in_sizes, int n_in,
                              void* d_out, int out_size, void* d_ws, size_t ws_size,
                              hipStream_t stream) {
    const float* fv       = (const float*)d_in[0];
    const float* and_W1   = (const float*)d_in[1];
    const float* and_b1   = (const float*)d_in[2];
    const float* and_W2   = (const float*)d_in[3];
    const float* and_b2   = (const float*)d_in[4];
    const float* or_W1    = (const float*)d_in[5];
    const float* or_b1    = (const float*)d_in[6];
    const float* or_W2    = (const float*)d_in[7];
    const float* or_b2    = (const float*)d_in[8];
    const float* not_W    = (const float*)d_in[9];
    const float* not_b    = (const float*)d_in[10];
    const int* not_idx    = (const int*)d_in[11];
    const int* and_pairs  = (const int*)d_in[12];
    const int* or_pairs   = (const int*)d_in[13];
    const int* leftover   = (const int*)d_in[14];
    float* out = (float*)d_out;
    char* ws = (char*)d_ws;

    // ws layout (bytes)
    unsigned short* fvb     = (unsigned short*)(ws);              // 64 MB bf16 fv
    unsigned short* and_W1T = (unsigned short*)(ws + 67108864);   // 1 MB
    unsigned short* or_W1T  = (unsigned short*)(ws + 68157440);   // 1 MB
    unsigned short* and_W2T = (unsigned short*)(ws + 69206016);   // 0.5 MB
    unsigned short* or_W2T  = (unsigned short*)(ws + 69730304);   // 0.5 MB
    unsigned short* not_WT  = (unsigned short*)(ws + 70254592);   // 0.5 MB

    PrepArgs pa;
    pa.fv = fv; pa.fvb = fvb; pa.out = out;
    pa.and_pairs = and_pairs; pa.or_pairs = or_pairs;
    pa.not_idx = not_idx; pa.lidx = leftover;
    pa.W[0] = and_W1; pa.WT[0] = and_W1T; pa.N[0] = 512;
    pa.W[1] = or_W1;  pa.WT[1] = or_W1T;  pa.N[1] = 512;
    pa.W[2] = and_W2; pa.WT[2] = and_W2T; pa.N[2] = 512;
    pa.W[3] = or_W2;  pa.WT[3] = or_W2T;  pa.N[3] = 512;
    pa.W[4] = not_W;  pa.WT[4] = not_WT;  pa.N[4] = 512;
    pa.tstart[0] = 0;   pa.tstart[1] = 128; pa.tstart[2] = 256;
    pa.tstart[3] = 320; pa.tstart[4] = 384; pa.tstart[5] = 448;
    prep_kernel<<<dim3(448 + 16384), dim3(256), 0, stream>>>(pa);

    FArgs fa;
    fa.fvb = fvb;
    fa.and_W1T = and_W1T; fa.and_W2T = and_W2T;
    fa.or_W1T = or_W1T;   fa.or_W2T = or_W2T;   fa.not_WT = not_WT;
    fa.and_pairs = and_pairs; fa.or_pairs = or_pairs; fa.not_idx = not_idx;
    fa.leftover = leftover;
    fa.and_b1 = and_b1; fa.and_b2 = and_b2;
    fa.or_b1 = or_b1;   fa.or_b2 = or_b2;   fa.not_b = not_b;
    fa.out = out;
    fused_phase<<<dim3(512), dim3(512), 0, stream>>>(fa);
}

// Round 10
// 298.679 us; speedup vs baseline: 1.2478x; 1.0141x over previous
//
#include <hip/hip_runtime.h>
#include <hip/hip_bf16.h>
#include <math.h>

// ---------- types ----------
typedef __attribute__((ext_vector_type(8))) __bf16 bf16x8;
typedef __attribute__((ext_vector_type(4))) float f32x4;

// fp32 -> bf16 round-to-nearest-even
__device__ __forceinline__ unsigned short f2bf(float f) {
    union { float f; unsigned u; } v; v.f = f;
    unsigned r = v.u + 0x7fffu + ((v.u >> 16) & 1u);
    return (unsigned short)(r >> 16);
}
// pack two fp32 into one dword of two bf16 (lo, hi)
__device__ __forceinline__ unsigned int pk(float a, float b) {
    union { float f; unsigned u; } x, y; x.f = a; y.f = b;
    unsigned ra = (x.u + 0x7fffu + ((x.u >> 16) & 1u)) >> 16;
    unsigned rb = (y.u + 0x7fffu + ((y.u >> 16) & 1u)) & 0xffff0000u;
    return ra | rb;
}

// async global->LDS, 16 B per lane; LDS dest = wave-uniform base + lane*16
__device__ __forceinline__ void gl2lds16(const unsigned short* g, unsigned short* l) {
    __builtin_amdgcn_global_load_lds(
        (const __attribute__((address_space(1))) unsigned int*)(g),
        (__attribute__((address_space(3))) unsigned int*)(l), 16, 0, 0);
}

// ---------- prep kernel ----------
// blocks [0,448): weight convert to MFMA FRAGMENT ORDER (round-8 layout):
//   WTf[kt][cg][lane][e]; B load in GEMM = base + lane*16, coalesced.
// blocks [448, 448+16384): fv streaming.  One wave = one field row; ballots
// give the wave-uniform consumer (and-slot / or-slot / not-slot / leftover).
// ROUND-9 LESSON: fused's A-staging was a 16-way split gather (rows 1-128 KB
// apart) on the latency-critical load path.  Prep now writes PRE-GATHERED,
// K-TILED, DMA-ORDERED A matrices so fused's stageA is one contiguous 1 KB
// per wave.  Layout: At[mt][kt][sub][lane][16B], where the 16 B at lane l of
// subtile sub holds row r = sub*16 + (l>>2) of the m-tile, k-chunk
// kc = (l&3) ^ (r&3)  (chunk-XOR swizzle baked in; inverse of the frag-read
// mapping l = (r&15)*4 + (kc ^ (r&3))).  The gather cost moves to prep's
// STORE side (fire-and-forget), traffic unchanged.
struct PrepArgs {
    const float* fv;
    unsigned short *and_At, *or_At, *not_At;
    const int *and_pairs, *or_pairs, *not_idx, *lidx;
    float* out;
    const float* W[5];
    unsigned short* WT[5];
    int N[5];
    int tstart[6];
};

__global__ __launch_bounds__(256) void prep_kernel(PrepArgs a) {
    __shared__ float tile[64][65];
    const int blk = blockIdx.x;
    const int tid = threadIdx.x;

    if (blk < 448) {
        int m = 0;
        while (blk >= a.tstart[m + 1]) m++;
        const float* src = a.W[m];
        unsigned short* dst = a.WT[m];
        const int N = a.N[m];
        const int t = blk - a.tstart[m];
        const int ntn = N >> 6;
        const int tk = t / ntn, tn = t % ntn;
        const int c = tid & 63, r0 = tid >> 6;
        #pragma unroll
        for (int r = r0; r < 64; r += 4)
            tile[r][c] = src[(size_t)(tk * 64 + r) * N + tn * 64 + c];
        __syncthreads();
        const int l = tid & 63;
        #pragma unroll
        for (int fi = tid >> 6; fi < 8; fi += 4) {
            const int ktl = fi & 1, cgl = fi >> 1;
            const int kt = tk * 2 + ktl, cg = tn * 4 + cgl;
            const int kb = ktl * 32 + (l >> 4) * 8;
            const int nb = cgl * 16 + (l & 15);
            uint4 o;
            o.x = pk(tile[kb + 0][nb], tile[kb + 1][nb]);
            o.y = pk(tile[kb + 2][nb], tile[kb + 3][nb]);
            o.z = pk(tile[kb + 4][nb], tile[kb + 5][nb]);
            o.w = pk(tile[kb + 6][nb], tile[kb + 7][nb]);
            ((uint4*)dst)[((size_t)kt * 32 + cg) * 64 + l] = o;
        }
        return;
    }

    const int t = (blk - 448) * 256 + tid;   // 8 consecutive floats
    const int lane = tid & 63;               // == 16B-chunk index c8 of the row
    const size_t e = (size_t)t * 8;
    const int c = (int)(e & 511);
    const int f = (int)((e >> 9) & 63);
    const int b = (int)(e >> 15);
    const float4 v0 = *(const float4*)(a.fv + e);
    const float4 v1 = *(const float4*)(a.fv + e + 4);
    const int am = (lane < 32) ? a.and_pairs[lane] : -1;
    const int om = (lane < 16) ? a.or_pairs[lane]  : -1;
    const int nm = (lane <  8) ? a.not_idx[lane]   : -1;
    const int lm = (lane < 16) ? a.lidx[lane]      : -1;
    const unsigned long long ba = __ballot(am == f);
    const unsigned long long bo = __ballot(om == f);
    const unsigned long long bn = __ballot(nm == f);
    const unsigned long long bl = __ballot(lm == f);

    uint4 o;
    o.x = pk(v0.x, v0.y); o.y = pk(v0.z, v0.w);
    o.z = pk(v1.x, v1.y); o.w = pk(v1.z, v1.w);
    const int c8 = lane;
    const int kc = c8 & 3;                   // chunk within a 32-k tile

    if (ba) {                                // and: m = b*16+p, k += s*512
        const int j = (int)__builtin_ctzll(ba);
        const int m = b * 16 + (j >> 1);
        const int kt = (j & 1) * 16 + (c8 >> 2);          // NTK=32
        const int r = m & 63;
        const int l = ((r & 15) << 2) | (kc ^ (r & 3));
        *(uint4*)(a.and_At +
            (((((size_t)(m >> 6) * 32 + kt) << 2) | (unsigned)(r >> 4)) << 9) +
            (l << 3)) = o;
    }
    if (bo) {                                // or: m = b*8+p
        const int j = (int)__builtin_ctzll(bo);
        const int m = b * 8 + (j >> 1);
        const int kt = (j & 1) * 16 + (c8 >> 2);          // NTK=32
        const int r = m & 63;
        const int l = ((r & 15) << 2) | (kc ^ (r & 3));
        *(uint4*)(a.or_At +
            (((((size_t)(m >> 6) * 32 + kt) << 2) | (unsigned)(r >> 4)) << 9) +
            (l << 3)) = o;
    }
    if (bn) {                                // not: m = b*8+i, K=512
        const int i = (int)__builtin_ctzll(bn);
        const int m = b * 8 + i;
        const int kt = c8 >> 2;                           // NTK=16
        const int r = m & 63;
        const int l = ((r & 15) << 2) | (kc ^ (r & 3));
        *(uint4*)(a.not_At +
            (((((size_t)(m >> 6) * 16 + kt) << 2) | (unsigned)(r >> 4)) << 9) +
            (l << 3)) = o;
    }
    if (bl && !bn) {   // leftover passthrough (not-fields written by tanh GEMM)
        const int ls = (int)__builtin_ctzll(bl);
        float* d = a.out + ((size_t)b * 40 + 24 + ls) * 512 + c;
        *(float4*)(d)     = v0;
        *(float4*)(d + 4) = v1;
    }
}

// ---------- fused two-layer GEMM segment ----------
// Block: BM=64 rows x ALL 512 cols, 8 waves, wave owns 64 cols: acc[4][4].
// A: pre-gathered k-tiled At -> stageA = ONE contiguous 1 KB gl2lds per
//    staging wave (waves 0..3), 4 buffers, staged 2 ahead.
// B: fragment-ordered, 4 coalesced 1-KB flat loads per step.
// Schedule (proved r6-r9): per step h: s_waitcnt vmcnt(1) lgkmcnt(0);
// s_barrier; LOADB B(h); [pin]; stageA(h+2); [pin]; ds_read; MMAC (implicit
// B(h)-wait retires A(h+1)-era ops); sched_barrier.  Issue order pinned
// B-before-A-stage so MMAC(h-1)'s wait retires A(h); h=0 covered by
// vmcnt(1) on [A0,A1]; WAR on 4 bufs covered by lgkmcnt(0)+barrier.
// hid LDS [64][512] bf16, 16B-chunk XOR swizzle -> L2-stage reads 2-way max.
// PATH 0: relu->hid(LDS)->L2->out fp32 (+bias), rows m=b*P+p, q=QBASE+p
// PATH 2: single layer, tanh->out, rows m=b*8+i, q=qmap[i]
#define LOADB(DST, WTP, K0)                                                  \
    _Pragma("unroll") for (int ni = 0; ni < 4; ni++)                         \
        DST[ni] = *(const bf16x8*)((WTP) +                                   \
            ((((size_t)(K0) >> 5) * 32 + cg0 + ni) << 9) + (lane << 3));

#define MMAC(BF, AF)                                                         \
    _Pragma("unroll") for (int mi = 0; mi < 4; mi++)                         \
    _Pragma("unroll") for (int ni = 0; ni < 4; ni++)                         \
        acc[mi][ni] = __builtin_amdgcn_mfma_f32_16x16x32_bf16(               \
            AF[mi], BF[ni], acc[mi][ni], 0, 0, 0);

template <int P, int K1, int PATH, int QBASE>
__device__ __forceinline__ void fused_seg(
    const unsigned short* __restrict__ At,
    const unsigned short* __restrict__ W1T,
    const float* __restrict__ b1,
    const unsigned short* __restrict__ W2T,
    const float* __restrict__ b2,
    float* __restrict__ out,
    const int* __restrict__ nidx,
    const int* __restrict__ leftover,
    int local,
    unsigned short* As, unsigned short* hid) {

    const int tid  = threadIdx.x;
    const int lane = tid & 63, w = tid >> 6;      // 8 waves
    const int ln15 = lane & 15;
    const int kq   = lane >> 4;                   // k-chunk quad 0..3
    const int wn   = w * 64;                      // wave's col base
    const int cg0  = w * 4;                       // wave's col-group base
    const int m0   = local * 64;                  // block's row base
    constexpr int NTK = K1 / 32;

    // A source: fully linear DMA stream (pre-gathered by prep)
    const unsigned short* abase =
        At + (size_t)local * NTK * 2048 + ((w & 3) << 9) + (lane << 3);
    auto stageA = [&](int buf, int t) {
        gl2lds16(abase + (size_t)t * 2048, &As[buf * 2048 + (w & 3) * 512]);
    };
    const int xsel = (kq ^ (lane & 3)) * 8;   // frag-read chunk slot

    f32x4 acc[4][4];
    #pragma unroll
    for (int mi = 0; mi < 4; mi++)
        #pragma unroll
        for (int ni = 0; ni < 4; ni++)
            acc[mi][ni] = f32x4{0.f, 0.f, 0.f, 0.f};

    bf16x8 bA[4];

    // ---- L1: acc = A[64,K1] @ W1[K1,512] ----
    if (w < 4) { stageA(0, 0); stageA(1, 1); }
    __builtin_amdgcn_sched_barrier(0);

    for (int h = 0; h < NTK; h++) {
        asm volatile("s_waitcnt vmcnt(1) lgkmcnt(0)" ::: "memory");
        asm volatile("s_barrier" ::: "memory");
        LOADB(bA, W1T, h * 32);                       // B(h) first
        __builtin_amdgcn_sched_barrier(0);            // pin B before A-stage
        if (w < 4 && h + 2 < NTK) stageA((h + 2) & 3, h + 2);
        __builtin_amdgcn_sched_barrier(0);
        bf16x8 af[4];
        #pragma unroll
        for (int mi = 0; mi < 4; mi++)
            af[mi] = *(const bf16x8*)&As[(h & 3) * 2048 +
                                         (mi * 16 + ln15) * 32 + xsel];
        MMAC(bA, af);                                 // waits B(h)
        __builtin_amdgcn_sched_barrier(0);
    }

    if constexpr (PATH == 2) {
        // single layer: tanh -> out at leftover slot
        int qmap[8];
        #pragma unroll
        for (int i = 0; i < 8; i++) {
            const int f = nidx[i];
            int q = 24;
            for (int l = 0; l < 16; l++)
                if (leftover[l] == f) q = 24 + l;
            qmap[i] = q;
        }
        #pragma unroll
        for (int ni = 0; ni < 4; ni++) {
            const int n = wn + ni * 16 + ln15;
            const float bv = b1[n];
            #pragma unroll
            for (int mi = 0; mi < 4; mi++)
                #pragma unroll
                for (int j = 0; j < 4; j++) {
                    const int r = mi * 16 + kq * 4 + j;
                    const int m = m0 + r;
                    const int b = m >> 3, i = m & 7;
                    out[((size_t)b * 40 + qmap[i]) * 512 + n] =
                        tanhf(acc[mi][ni][j] + bv);
                }
        }
        return;
    }

    // ---- L1 epilogue: relu -> bf16 -> hid LDS (XOR-swizzled chunks) ----
    #pragma unroll
    for (int ni = 0; ni < 4; ni++) {
        const int n  = wn + ni * 16 + ln15;
        const float bv = b1[n];
        const int c8 = n >> 3;
        const int cl = (n & 7) * 2;
        #pragma unroll
        for (int mi = 0; mi < 4; mi++)
            #pragma unroll
            for (int j = 0; j < 4; j++) {
                const int r = mi * 16 + kq * 4 + j;
                float v = acc[mi][ni][j] + bv;
                v = v > 0.f ? v : 0.f;
                *(unsigned short*)((char*)hid + r * 1024 +
                                   ((c8 ^ (r & 7)) * 16) + cl) = f2bf(v);
            }
    }
    #pragma unroll
    for (int mi = 0; mi < 4; mi++)
        #pragma unroll
        for (int ni = 0; ni < 4; ni++)
            acc[mi][ni] = f32x4{0.f, 0.f, 0.f, 0.f};
    __syncthreads();                       // hid visible (full drain, once)

    // ---- L2: acc = hid[64,512] @ W2[512,512], A from LDS, no barriers ----
    for (int t2 = 0; t2 < 16; t2++) {
        LOADB(bA, W2T, t2 * 32);
        bf16x8 af[4];
        #pragma unroll
        for (int mi = 0; mi < 4; mi++) {
            const int r = mi * 16 + ln15;
            const int c8 = t2 * 4 + kq;
            af[mi] = *(const bf16x8*)((char*)hid + r * 1024 +
                                      ((c8 ^ (r & 7)) * 16));
        }
        MMAC(bA, af);
    }

    // ---- L2 epilogue: +bias -> fp32 out ----
    #pragma unroll
    for (int ni = 0; ni < 4; ni++) {
        const int n  = wn + ni * 16 + ln15;
        const float bv = b2[n];
        #pragma unroll
        for (int mi = 0; mi < 4; mi++)
            #pragma unroll
            for (int j = 0; j < 4; j++) {
                const int r = mi * 16 + kq * 4 + j;
                const int m = m0 + r;
                const int b = m / P, p = m % P;    // P constexpr -> shifts
                out[((size_t)b * 40 + QBASE + p) * 512 + n] =
                    acc[mi][ni][j] + bv;
            }
    }
}

// ---------- fused phase kernel ----------
struct FArgs {
    const unsigned short *and_At, *or_At, *not_At;
    const unsigned short *and_W1T, *and_W2T, *or_W1T, *or_W2T, *not_WT;
    const int *not_idx, *leftover;
    const float *and_b1, *and_b2, *or_b1, *or_b2, *not_b;
    float* out;
};

__global__ __launch_bounds__(512, 4) void fused_phase(FArgs a) {
    __shared__ __align__(16) unsigned short As[4 * 64 * 32];   // 16 KB, 4 bufs
    __shared__ __align__(16) unsigned short hid[64 * 512];     // 64 KB
    const int blk = blockIdx.x;
    if (blk < 256)        // and: M=16384 -> 256 blocks of 64 rows
        fused_seg<16, 1024, 0, 0>(a.and_At, a.and_W1T, a.and_b1,
                                  a.and_W2T, a.and_b2, a.out,
                                  nullptr, nullptr, blk, As, hid);
    else if (blk < 384)   // or: M=8192 -> 128 blocks
        fused_seg<8, 1024, 0, 16>(a.or_At, a.or_W1T, a.or_b1,
                                  a.or_W2T, a.or_b2, a.out,
                                  nullptr, nullptr, blk - 256, As, hid);
    else                  // not: M=8192, single layer tanh -> 128 blocks
        fused_seg<8, 512, 2, 24>(a.not_At, a.not_WT, a.not_b,
                                 nullptr, nullptr, a.out,
                                 a.not_idx, a.leftover, blk - 384, As, hid);
}

// ---------- launch ----------
extern "C" void kernel_launch(void* const* d_in, const int* in_sizes, int n_in,
                              void* d_out, int out_size, void* d_ws, size_t ws_size,
                              hipStream_t stream) {
    const float* fv       = (const float*)d_in[0];
    const float* and_W1   = (const float*)d_in[1];
    const float* and_b1   = (const float*)d_in[2];
    const float* and_W2   = (const float*)d_in[3];
    const float* and_b2   = (const float*)d_in[4];
    const float* or_W1    = (const float*)d_in[5];
    const float* or_b1    = (const float*)d_in[6];
    const float* or_W2    = (const float*)d_in[7];
    const float* or_b2    = (const float*)d_in[8];
    const float* not_W    = (const float*)d_in[9];
    const float* not_b    = (const float*)d_in[10];
    const int* not_idx    = (const int*)d_in[11];
    const int* and_pairs  = (const int*)d_in[12];
    const int* or_pairs   = (const int*)d_in[13];
    const int* leftover   = (const int*)d_in[14];
    float* out = (float*)d_out;
    char* ws = (char*)d_ws;

    // ws layout (bytes)
    unsigned short* and_At  = (unsigned short*)(ws);              // 32 MB
    unsigned short* or_At   = (unsigned short*)(ws + 33554432);   // 16 MB
    unsigned short* not_At  = (unsigned short*)(ws + 50331648);   // 8 MB
    unsigned short* and_W1T = (unsigned short*)(ws + 58720256);   // 1 MB
    unsigned short* or_W1T  = (unsigned short*)(ws + 59768832);   // 1 MB
    unsigned short* and_W2T = (unsigned short*)(ws + 60817408);   // 0.5 MB
    unsigned short* or_W2T  = (unsigned short*)(ws + 61341696);   // 0.5 MB
    unsigned short* not_WT  = (unsigned short*)(ws + 61865984);   // 0.5 MB

    PrepArgs pa;
    pa.fv = fv; pa.out = out;
    pa.and_At = and_At; pa.or_At = or_At; pa.not_At = not_At;
    pa.and_pairs = and_pairs; pa.or_pairs = or_pairs;
    pa.not_idx = not_idx; pa.lidx = leftover;
    pa.W[0] = and_W1; pa.WT[0] = and_W1T; pa.N[0] = 512;
    pa.W[1] = or_W1;  pa.WT[1] = or_W1T;  pa.N[1] = 512;
    pa.W[2] = and_W2; pa.WT[2] = and_W2T; pa.N[2] = 512;
    pa.W[3] = or_W2;  pa.WT[3] = or_W2T;  pa.N[3] = 512;
    pa.W[4] = not_W;  pa.WT[4] = not_WT;  pa.N[4] = 512;
    pa.tstart[0] = 0;   pa.tstart[1] = 128; pa.tstart[2] = 256;
    pa.tstart[3] = 320; pa.tstart[4] = 384; pa.tstart[5] = 448;
    prep_kernel<<<dim3(448 + 16384), dim3(256), 0, stream>>>(pa);

    FArgs fa;
    fa.and_At = and_At; fa.or_At = or_At; fa.not_At = not_At;
    fa.and_W1T = and_W1T; fa.and_W2T = and_W2T;
    fa.or_W1T = or_W1T;   fa.or_W2T = or_W2T;   fa.not_WT = not_WT;
    fa.not_idx = not_idx; fa.leftover = leftover;
    fa.and_b1 = and_b1; fa.and_b2 = and_b2;
    fa.or_b1 = or_b1;   fa.or_b2 = or_b2;   fa.not_b = not_b;
    fa.out = out;
    fused_phase<<<dim3(512), dim3(512), 0, stream>>>(fa);
}